// Round 9
// baseline (440.853 us; speedup 1.0000x reference)
//
#include <hip/hip_runtime.h>
#include <stdint.h>

// SNN forward (Mozafari 2018), max_layer==2:
//   pad(2) -> conv1(30,6,5,5) -> fire(>15) -> maxpool2x2 -> pad(1)
//   -> conv2(240,30,3,3) -> fire(>10) -> out = spk ++ pot (f32)
//
// f16 MFMA implicit GEMM.
//  conv1: ~14us (r3 diag). Chunked-XCD swizzle, dual f16 input copies,
//         pool-interleaved M, one b128 per A-frag.
//  conv2: r4 LDS-transpose epilogue (64B->256B store runs) fixed the TCC
//         RMW storm (c2 230->~112us). r5/r7/r8 (B placement, XCD swizzle,
//         1KB single-channel runs) all neutral -> granularity saturated at
//         256B, residual WRITE amp 1.56x (r6: 565MB/rep vs 361 mandatory)
//         is NOT geometric. r9 SINGLE-VARIABLE TEST: drop the nt hint —
//         if the TCC forwards nt sectors unmerged, the amp is intrinsic to
//         nt; write-back L2 evicts full-dirty lines instead. B is LDS-
//         staged (thrash-immune) and A slices are 1.5MB/XCD, so the
//         original nt rationale is gone.

typedef _Float16 half8  __attribute__((ext_vector_type(8)));
typedef _Float16 half8u __attribute__((ext_vector_type(8), aligned(4)));
typedef float f32x4  __attribute__((ext_vector_type(4)));

#define POT1_T 15.0f
#define POT2_T 10.0f

// ---- ws layout (all 16B aligned) ----
#define SPK_ELEMS  (15*114*114*32)            // 6,238,080 f16 (ch-interleaved, padded)
#define SPK_BYTES  (SPK_ELEMS*2)              // 12,476,160
#define BP2_OFF    SPK_BYTES
#define BP2_BYTES  (9*15*64*8*2)              // 138,240
#define BP1_OFF    (BP2_OFF + BP2_BYTES)
#define BP1_BYTES  (8*2*64*8*2)               // 16,384
#define IN16_OFF   (BP1_OFF + BP1_BYTES)      // 12,630,784 (16B aligned)
#define IN16_ELEMS (90*228*228)               // 4,678,560 f16 per copy

#define PAD_BLOCKS ((IN16_ELEMS + 255) / 256) // 18276

#define RING_UINT4  (15 * 452 * 4)            // 27120
#define RING_BLOCKS ((RING_UINT4 + 255) / 256)

__device__ __forceinline__ unsigned short f2h(float v) {
  union { _Float16 h; unsigned short u; } c;
  c.h = (_Float16)v;                          // RNE
  return c.u;
}

// ---------------------------------------------------------------------------
// prep: pad input -> f16, dual copies (ina[i]=v(i), inb[i-1]=v(i)), weight
// packing to MFMA B-frag layout [step][nsub][lane][8], and spike-map pad-ring
// zeroing (replaces a 12.5 MB memset).
// ---------------------------------------------------------------------------
__global__ __launch_bounds__(256) void prep(
    const float* __restrict__ in, const float* __restrict__ w1,
    const float* __restrict__ w2, unsigned short* __restrict__ ina,
    unsigned short* __restrict__ bp2, unsigned short* __restrict__ bp1,
    unsigned short* __restrict__ spk16)
{
  const int blk = blockIdx.x;
  if (blk < PAD_BLOCKS) {
    const int i = blk * 256 + threadIdx.x;
    if (i >= IN16_ELEMS) return;
    const int xx = i % 228, t = i / 228;
    const int yy = t % 228, c = t / 228;
    const int xi = xx - 2, yi = yy - 2;
    float v = 0.0f;
    if ((unsigned)xi < 224u && (unsigned)yi < 224u)
      v = in[(c * 224 + yi) * 224 + xi];
    const unsigned short h = f2h(v);
    unsigned short* inb = ina + IN16_ELEMS;
    ina[i] = h;
    if (i > 0) inb[i - 1] = h;
    if (i == IN16_ELEMS - 1) inb[i] = 0;
    return;
  }
  const int b = blk - PAD_BLOCKS;              // 0..150 weights, 151.. ring
  if (b >= 151) {                              // ---- pad-ring zero ----
    const int idx = (b - 151) * 256 + threadIdx.x;
    if (idx >= RING_UINT4) return;
    const int part = idx & 3, cell = idx >> 2;
    const int n = cell / 452, rp = cell - n * 452;
    int y, x;
    if (rp < 114)      { y = 0;   x = rp; }
    else if (rp < 228) { y = 113; x = rp - 114; }
    else {
      const int r2 = rp - 228;                 // 0..223
      x = (r2 & 1) ? 113 : 0;
      y = 1 + (r2 >> 1);                       // 1..112
    }
    const int off = ((n * 114 + y) * 114 + x) * 32 + part * 8;
    *(uint4*)(spk16 + off) = (uint4){0u, 0u, 0u, 0u};
    return;
  }
  if (threadIdx.x >= 64) return;
  const int lane = threadIdx.x;
  const int quad = lane >> 4, nl = lane & 15;
  if (b < 135) {                               // conv2: 9 steps x 15 nsub
    const int s = b / 15, nsub = b - s * 15;   // s = ky*3+kx
    const int ch = nsub * 16 + nl;
    unsigned short* dst = bp2 + (((s * 15 + nsub) * 64 + lane) << 3);
    #pragma unroll
    for (int j = 0; j < 8; ++j) {
      const int ci = quad * 8 + j;
      dst[j] = f2h((ci < 30) ? w2[ch * 270 + ci * 9 + s] : 0.0f);
    }
  } else {                                     // conv1: 8 steps x 2 nsub
    const int bb = b - 135;
    const int s = bb >> 1, nsub = bb & 1;
    const int ch = nsub * 16 + nl;
    unsigned short* dst = bp1 + (((s * 2 + nsub) * 64 + lane) << 3);
    #pragma unroll
    for (int j = 0; j < 8; ++j) {
      int ci, ky;
      bool ok = (ch < 30) && (j < 5);
      if (s < 6)       { ci = s;        ky = quad; }
      else if (s == 6) { ci = quad;     ky = 4;    }
      else             { ci = 4 + quad; ky = 4; ok = ok && (quad < 2); }
      float v = 0.0f;
      if (ok) v = w1[ch * 150 + ci * 25 + ky * 5 + j];
      dst[j] = f2h(v);
    }
  }
}

// ---------------------------------------------------------------------------
// conv1 + fire + maxpool2x2. Pool-interleaved M. M=64/wave. A-frag = one
// 4B-aligned b128 from the parity-matched input copy. grid 2940 x 256.
// Chunked-XCD swizzle (bijective, q=367 r=4). ~14us measured (r3).
// ---------------------------------------------------------------------------
__global__ __launch_bounds__(256) void conv1_mfma(
    const unsigned short* __restrict__ in16,   // ina; inb = ina + IN16_ELEMS
    const unsigned short* __restrict__ bp1,
    unsigned short* __restrict__ spk16)
{
  const int tid = threadIdx.x;
  const int wave = tid >> 6, lane = tid & 63;
  const int quad = lane >> 4, nl = lane & 15;

  // bijective chunked XCD swizzle of 2940 blocks: q=367, r=4
  const int bid = blockIdx.x;
  const int xcd = bid & 7, pos = bid >> 3;
  const int sb = (xcd < 4) ? (xcd * 368 + pos)
                           : (4 * 368 + (xcd - 4) * 367 + pos);
  const int m0 = sb * 256 + wave * 64;

  // parity of x0 is lane-constant: p = nl & 1 (m0, c*16 even)
  const unsigned short* base = in16 + ((nl & 1) ? (IN16_ELEMS - 1) : 0);

  unsigned o_q[4], o_a[4], o_b[4];
  #pragma unroll
  for (int c = 0; c < 4; ++c) {
    const int m = m0 + c * 16 + nl;
    const int sub = m & 3, g = m >> 2;
    const int gx = g % 112, t = g / 112;
    const int gy = t % 112, n = t / 112;
    const int y0 = gy * 2 + (sub >> 1);        // padded coords
    const int x0 = gx * 2 + (sub & 1);
    const unsigned nb = (unsigned)n * 311904u; // 6*51984
    o_q[c] = nb + (unsigned)((y0 + quad) * 228 + x0);
    o_a[c] = nb + (unsigned)quad * 51984u + (unsigned)((y0 + 4) * 228 + x0);
    o_b[c] = nb + (unsigned)(4 + (quad & 1)) * 51984u + (unsigned)((y0 + 4) * 228 + x0);
  }

  f32x4 acc[4][2];
  #pragma unroll
  for (int c = 0; c < 4; ++c) {
    acc[c][0] = (f32x4){0.f, 0.f, 0.f, 0.f};
    acc[c][1] = (f32x4){0.f, 0.f, 0.f, 0.f};
  }

  const half8* bptr = (const half8*)bp1;
  #pragma unroll
  for (int s = 0; s < 8; ++s) {
    const half8 b0 = bptr[(s * 2 + 0) * 64 + lane];
    const half8 b1 = bptr[(s * 2 + 1) * 64 + lane];
    #pragma unroll
    for (int c = 0; c < 4; ++c) {
      const unsigned off = (s < 6) ? (o_q[c] + (unsigned)s * 51984u)
                                   : (s == 6 ? o_a[c] : o_b[c]);
      const half8 A = *(const half8u*)(base + off);
      acc[c][0] = __builtin_amdgcn_mfma_f32_16x16x32_f16(A, b0, acc[c][0], 0, 0, 0);
      acc[c][1] = __builtin_amdgcn_mfma_f32_16x16x32_f16(A, b1, acc[c][1], 0, 0, 0);
    }
  }

  #pragma unroll
  for (int c = 0; c < 4; ++c) {
    const int gq = ((m0 + c * 16) >> 2) + quad;
    const int pgx = gq % 112, tq = gq / 112;
    const int pgy = tq % 112, nq = tq / 112;
    const bool f0 = (acc[c][0][0] > POT1_T) | (acc[c][0][1] > POT1_T) |
                    (acc[c][0][2] > POT1_T) | (acc[c][0][3] > POT1_T);
    const bool f1 = (acc[c][1][0] > POT1_T) | (acc[c][1][1] > POT1_T) |
                    (acc[c][1][2] > POT1_T) | (acc[c][1][3] > POT1_T);
    const size_t o = ((size_t)(nq * 114 + pgy + 1) * 114 + (pgx + 1)) * 32 + nl;
    spk16[o] = f0 ? (unsigned short)0x3C00 : (unsigned short)0;
    // ch>=30 weights are zero-packed -> acc==0 -> stores 0 (inits ch 30/31)
    spk16[o + 16] = f1 ? (unsigned short)0x3C00 : (unsigned short)0;
  }
}

// ---------------------------------------------------------------------------
// conv2 + fire: block = 4 waves x M=64 = 256 rows; N = 5 subtiles (80 ch),
// 3 N-tiles cover 240. B staged in LDS (45KB, once per block). Subtiles in
// two groups (3 then 2). Block-wide transpose epilogue: per subtile, 4
// waves dump pot into one 16KB buffer (phys chunk = j ^ (ch&7), bank-clean
// both sides); store phase: wave w stores ch w*4..w*4+3, each store = 1KB
// of ONE channel as a single contiguous 256B-aligned run (block m-run =
// 256 consecutive m; 12544 = 49*256 -> no n crossing).
// r9: PLAIN stores (no nt) — write-back L2 merges full-dirty lines; tests
// whether the residual 1.56x WRITE amp was intrinsic to the nt path.
// LDS 61KB -> 2 blocks/CU. grid 2208 x 256, chunked-XCD swizzle.
// ---------------------------------------------------------------------------
#define C2_NSUB 5
__global__ __launch_bounds__(256, 2) void conv2_mfma(
    const unsigned short* __restrict__ spk16,
    const unsigned short* __restrict__ bp2,
    float* __restrict__ out_spk, float* __restrict__ out_pot)
{
  __shared__ __attribute__((aligned(16))) unsigned short Blds[C2_NSUB * 9 * 64 * 8];
  __shared__ __attribute__((aligned(16))) float Tlds[4096];   // 16KB block-wide

  const int tid = threadIdx.x;

  // chunked-XCD swizzle: gid -> (bx, ntile)
  const int gid = blockIdx.x;                  // 0..2207
  const int xcd = gid & 7, pos = gid >> 3;     // pos 0..275
  const int bxq = pos / 3;                     // 0..91
  const int bx = xcd * 92 + bxq;               // 0..735
  const int ntile = pos - bxq * 3;             // 0..2
  if (bx >= 735) return;                       // 3 idle blocks (uniform exit)

  // stage B: 5 subtiles x 9 steps x 64 lanes x 16B = 2880 uint4
  for (int i = tid; i < 2880; i += 256) {
    const int su = i / 576, rem = i - su * 576;    // rem = s*64+lane
    ((uint4*)Blds)[su * 576 + rem] =
        ((const uint4*)bp2)[((rem >> 6) * 15 + ntile * C2_NSUB + su) * 64 + (rem & 63)];
  }
  __syncthreads();

  const int wave = tid >> 6, lane = tid & 63;
  const int quad = lane >> 4, nl = lane & 15;
  const int m0 = bx * 256 + wave * 64;         // per-wave 64-m run, 64-aligned

  const unsigned short* abase[4];
  #pragma unroll
  for (int c = 0; c < 4; ++c) {
    const int m = m0 + c * 16 + nl;
    const int x = m % 112, t = m / 112;
    const int y = t % 112, n = t / 112;
    abase[c] = spk16 + ((size_t)(n * 114 + y) * 114 + x) * 32 + quad * 8;
  }

  // block's flat-contiguous output run: 12544 = 49*256 -> never crosses n
  const int nrb = bx / 49;
  const int offb = (bx - nrb * 49) * 256;

  const half8* blds = (const half8*)Blds;

  #pragma unroll
  for (int g = 0; g < 2; ++g) {
    const int ub = g ? 3 : 0;                  // subtile base of this group
    const int uc = g ? 2 : 3;                  // subtiles in this group

    f32x4 acc[4][3];
    #pragma unroll
    for (int c = 0; c < 4; ++c)
      #pragma unroll
      for (int u2 = 0; u2 < 3; ++u2) acc[c][u2] = (f32x4){0.f, 0.f, 0.f, 0.f};

    #pragma unroll
    for (int s = 0; s < 9; ++s) {              // s = ky*3+kx
      const int ky = s / 3, kx = s - ky * 3;   // compile-time under unroll
      half8 a[4];
      #pragma unroll
      for (int c = 0; c < 4; ++c)
        a[c] = *(const half8*)(abase[c] + (ky * 114 + kx) * 32);
      #pragma unroll
      for (int u2 = 0; u2 < 3; ++u2) {
        if (u2 < uc) {
          const half8 b = blds[((ub + u2) * 9 + s) * 64 + lane];
          #pragma unroll
          for (int c = 0; c < 4; ++c)
            acc[c][u2] = __builtin_amdgcn_mfma_f32_16x16x32_f16(a[c], b, acc[c][u2], 0, 0, 0);
        }
      }
    }

    // ---- block-wide transpose epilogue: 1KB single-channel stores ----
    // acc[c][u2][rr] @ lane(quad,nl), wave w = pot(m = m0 + (c*4+quad)*4+rr,
    //                                              ch = chbase + nl).
    // Logical T[ch][chunk j][4], j = block m-chunk = w*16 + c*4 + quad;
    // phys float off = ch*256 + (j ^ (ch&7))*4 (bank-clean both phases).
    // Store: wave w covers ch w*4..w*4+3; lane l reads chunk j=l -> one
    // 1KB contiguous aligned run per store.
    #pragma unroll
    for (int u2 = 0; u2 < 3; ++u2) {
      if (u2 < uc) {
        __syncthreads();                       // prior store-phase reads done
        #pragma unroll
        for (int c = 0; c < 4; ++c) {
          const int j = wave * 16 + c * 4 + quad;
          *(f32x4*)(Tlds + nl * 256 + ((j ^ (nl & 7)) << 2)) = acc[c][u2];
        }
        __syncthreads();                       // dump visible to all waves
        const int chb = (ntile * C2_NSUB + ub + u2) * 16;
        #pragma unroll
        for (int k = 0; k < 4; ++k) {
          const int chr = wave * 4 + k;        // source channel 0..15
          const f32x4 p4 =
              *(const f32x4*)(Tlds + chr * 256 + ((lane ^ (chr & 7)) << 2));
          const size_t dst =
              (size_t)(nrb * 240 + chb + chr) * 12544 + offb + lane * 4;
          f32x4 sp, pt;
          #pragma unroll
          for (int rr = 0; rr < 4; ++rr) {
            const bool f = p4[rr] > POT2_T;
            sp[rr] = f ? 1.0f : 0.0f;
            pt[rr] = f ? p4[rr] : 0.0f;
          }
          *(f32x4*)(out_spk + dst) = sp;       // plain stores (r9: nt A/B)
          *(f32x4*)(out_pot + dst) = pt;
        }
      }
    }
    __builtin_amdgcn_sched_barrier(0);
  }
}

// ---------------------------------------------------------------------------
extern "C" void kernel_launch(void* const* d_in, const int* in_sizes, int n_in,
                              void* d_out, int out_size, void* d_ws, size_t ws_size,
                              hipStream_t stream)
{
  const float* in = (const float*)d_in[0];
  const float* w1 = (const float*)d_in[1];
  const float* w2 = (const float*)d_in[2];
  float* out = (float*)d_out;

  unsigned short* spk16 = (unsigned short*)d_ws;
  unsigned short* bp2   = (unsigned short*)((char*)d_ws + BP2_OFF);
  unsigned short* bp1   = (unsigned short*)((char*)d_ws + BP1_OFF);
  unsigned short* ina   = (unsigned short*)((char*)d_ws + IN16_OFF);

  prep<<<PAD_BLOCKS + 151 + RING_BLOCKS, 256, 0, stream>>>(
      in, w1, w2, ina, bp2, bp1, spk16);
  conv1_mfma<<<2940, 256, 0, stream>>>(ina, bp1, spk16);
  conv2_mfma<<<2208, 256, 0, stream>>>(
      spk16, bp2, out, out + (size_t)15 * 240 * 112 * 112);
}

// Round 10
// 422.789 us; speedup vs baseline: 1.0427x; 1.0427x over previous
//
#include <hip/hip_runtime.h>
#include <stdint.h>

// SNN forward (Mozafari 2018), max_layer==2:
//   pad(2) -> conv1(30,6,5,5) -> fire(>15) -> maxpool2x2 -> pad(1)
//   -> conv2(240,30,3,3) -> fire(>10) -> out = spk ++ pot (f32)
//
// f16 MFMA implicit GEMM.
//  conv1: ~14us (r3). Chunked-XCD swizzle, dual f16 copies, pool-interleaved
//         M, one b128 per A-frag.
//  conv2 history: r4 LDS-transpose epilogue (64->256B runs) fixed TCC RMW
//         (c2 230->112). r5 occ/B, r7 XCD, r8 1KB runs: null. r9 plain
//         stores REGRESSED (440.9) -> nt restored (write-allocate evicts
//         A-lines; nt no-allocate is right for the 361MB stream).
//  r10 theory: conv2 is LATENCY-bound on A-loads missing to HBM (r6:
//         FETCH 449MB/rep vs 12.5MB map, 39% BW, all pipes <5%; 4 dependent
//         loads/step feeding 20 MFMAs, ~900cyc misses, 8-16 waves can't
//         hide). FIX: stage A in LDS — block's 256-m run needs <=6
//         contiguous rows = ONE contiguous 43.8KB region (layout (n,y,x,32),
//         12544=49*256 -> no n-crossing). Bulk copy once per block; inner
//         A-reads become ds_read_b128. B direct from L2 (135KB, r5-neutral).
//         LDS 60KB -> 2 blocks/CU.

typedef _Float16 half8  __attribute__((ext_vector_type(8)));
typedef _Float16 half8u __attribute__((ext_vector_type(8), aligned(4)));
typedef float f32x4  __attribute__((ext_vector_type(4)));

#define POT1_T 15.0f
#define POT2_T 10.0f

// ---- ws layout (all 16B aligned) ----
#define SPK_ELEMS  (15*114*114*32)            // 6,238,080 f16 (ch-interleaved, padded)
#define SPK_BYTES  (SPK_ELEMS*2)              // 12,476,160
#define BP2_OFF    SPK_BYTES
#define BP2_BYTES  (9*15*64*8*2)              // 138,240
#define BP1_OFF    (BP2_OFF + BP2_BYTES)
#define BP1_BYTES  (8*2*64*8*2)               // 16,384
#define IN16_OFF   (BP1_OFF + BP1_BYTES)      // 12,630,784 (16B aligned)
#define IN16_ELEMS (90*228*228)               // 4,678,560 f16 per copy

#define PAD_BLOCKS ((IN16_ELEMS + 255) / 256) // 18276

#define RING_UINT4  (15 * 452 * 4)            // 27120
#define RING_BLOCKS ((RING_UINT4 + 255) / 256)

__device__ __forceinline__ unsigned short f2h(float v) {
  union { _Float16 h; unsigned short u; } c;
  c.h = (_Float16)v;                          // RNE
  return c.u;
}

// ---------------------------------------------------------------------------
// prep: pad input -> f16, dual copies (ina[i]=v(i), inb[i-1]=v(i)), weight
// packing to MFMA B-frag layout [step][nsub][lane][8], and spike-map pad-ring
// zeroing (replaces a 12.5 MB memset).
// ---------------------------------------------------------------------------
__global__ __launch_bounds__(256) void prep(
    const float* __restrict__ in, const float* __restrict__ w1,
    const float* __restrict__ w2, unsigned short* __restrict__ ina,
    unsigned short* __restrict__ bp2, unsigned short* __restrict__ bp1,
    unsigned short* __restrict__ spk16)
{
  const int blk = blockIdx.x;
  if (blk < PAD_BLOCKS) {
    const int i = blk * 256 + threadIdx.x;
    if (i >= IN16_ELEMS) return;
    const int xx = i % 228, t = i / 228;
    const int yy = t % 228, c = t / 228;
    const int xi = xx - 2, yi = yy - 2;
    float v = 0.0f;
    if ((unsigned)xi < 224u && (unsigned)yi < 224u)
      v = in[(c * 224 + yi) * 224 + xi];
    const unsigned short h = f2h(v);
    unsigned short* inb = ina + IN16_ELEMS;
    ina[i] = h;
    if (i > 0) inb[i - 1] = h;
    if (i == IN16_ELEMS - 1) inb[i] = 0;
    return;
  }
  const int b = blk - PAD_BLOCKS;              // 0..150 weights, 151.. ring
  if (b >= 151) {                              // ---- pad-ring zero ----
    const int idx = (b - 151) * 256 + threadIdx.x;
    if (idx >= RING_UINT4) return;
    const int part = idx & 3, cell = idx >> 2;
    const int n = cell / 452, rp = cell - n * 452;
    int y, x;
    if (rp < 114)      { y = 0;   x = rp; }
    else if (rp < 228) { y = 113; x = rp - 114; }
    else {
      const int r2 = rp - 228;                 // 0..223
      x = (r2 & 1) ? 113 : 0;
      y = 1 + (r2 >> 1);                       // 1..112
    }
    const int off = ((n * 114 + y) * 114 + x) * 32 + part * 8;
    *(uint4*)(spk16 + off) = (uint4){0u, 0u, 0u, 0u};
    return;
  }
  if (threadIdx.x >= 64) return;
  const int lane = threadIdx.x;
  const int quad = lane >> 4, nl = lane & 15;
  if (b < 135) {                               // conv2: 9 steps x 15 nsub
    const int s = b / 15, nsub = b - s * 15;   // s = ky*3+kx
    const int ch = nsub * 16 + nl;
    unsigned short* dst = bp2 + (((s * 15 + nsub) * 64 + lane) << 3);
    #pragma unroll
    for (int j = 0; j < 8; ++j) {
      const int ci = quad * 8 + j;
      dst[j] = f2h((ci < 30) ? w2[ch * 270 + ci * 9 + s] : 0.0f);
    }
  } else {                                     // conv1: 8 steps x 2 nsub
    const int bb = b - 135;
    const int s = bb >> 1, nsub = bb & 1;
    const int ch = nsub * 16 + nl;
    unsigned short* dst = bp1 + (((s * 2 + nsub) * 64 + lane) << 3);
    #pragma unroll
    for (int j = 0; j < 8; ++j) {
      int ci, ky;
      bool ok = (ch < 30) && (j < 5);
      if (s < 6)       { ci = s;        ky = quad; }
      else if (s == 6) { ci = quad;     ky = 4;    }
      else             { ci = 4 + quad; ky = 4; ok = ok && (quad < 2); }
      float v = 0.0f;
      if (ok) v = w1[ch * 150 + ci * 25 + ky * 5 + j];
      dst[j] = f2h(v);
    }
  }
}

// ---------------------------------------------------------------------------
// conv1 + fire + maxpool2x2. Pool-interleaved M. M=64/wave. A-frag = one
// 4B-aligned b128 from the parity-matched input copy. grid 2940 x 256.
// Chunked-XCD swizzle (bijective, q=367 r=4). ~14us measured (r3).
// ---------------------------------------------------------------------------
__global__ __launch_bounds__(256) void conv1_mfma(
    const unsigned short* __restrict__ in16,   // ina; inb = ina + IN16_ELEMS
    const unsigned short* __restrict__ bp1,
    unsigned short* __restrict__ spk16)
{
  const int tid = threadIdx.x;
  const int wave = tid >> 6, lane = tid & 63;
  const int quad = lane >> 4, nl = lane & 15;

  // bijective chunked XCD swizzle of 2940 blocks: q=367, r=4
  const int bid = blockIdx.x;
  const int xcd = bid & 7, pos = bid >> 3;
  const int sb = (xcd < 4) ? (xcd * 368 + pos)
                           : (4 * 368 + (xcd - 4) * 367 + pos);
  const int m0 = sb * 256 + wave * 64;

  // parity of x0 is lane-constant: p = nl & 1 (m0, c*16 even)
  const unsigned short* base = in16 + ((nl & 1) ? (IN16_ELEMS - 1) : 0);

  unsigned o_q[4], o_a[4], o_b[4];
  #pragma unroll
  for (int c = 0; c < 4; ++c) {
    const int m = m0 + c * 16 + nl;
    const int sub = m & 3, g = m >> 2;
    const int gx = g % 112, t = g / 112;
    const int gy = t % 112, n = t / 112;
    const int y0 = gy * 2 + (sub >> 1);        // padded coords
    const int x0 = gx * 2 + (sub & 1);
    const unsigned nb = (unsigned)n * 311904u; // 6*51984
    o_q[c] = nb + (unsigned)((y0 + quad) * 228 + x0);
    o_a[c] = nb + (unsigned)quad * 51984u + (unsigned)((y0 + 4) * 228 + x0);
    o_b[c] = nb + (unsigned)(4 + (quad & 1)) * 51984u + (unsigned)((y0 + 4) * 228 + x0);
  }

  f32x4 acc[4][2];
  #pragma unroll
  for (int c = 0; c < 4; ++c) {
    acc[c][0] = (f32x4){0.f, 0.f, 0.f, 0.f};
    acc[c][1] = (f32x4){0.f, 0.f, 0.f, 0.f};
  }

  const half8* bptr = (const half8*)bp1;
  #pragma unroll
  for (int s = 0; s < 8; ++s) {
    const half8 b0 = bptr[(s * 2 + 0) * 64 + lane];
    const half8 b1 = bptr[(s * 2 + 1) * 64 + lane];
    #pragma unroll
    for (int c = 0; c < 4; ++c) {
      const unsigned off = (s < 6) ? (o_q[c] + (unsigned)s * 51984u)
                                   : (s == 6 ? o_a[c] : o_b[c]);
      const half8 A = *(const half8u*)(base + off);
      acc[c][0] = __builtin_amdgcn_mfma_f32_16x16x32_f16(A, b0, acc[c][0], 0, 0, 0);
      acc[c][1] = __builtin_amdgcn_mfma_f32_16x16x32_f16(A, b1, acc[c][1], 0, 0, 0);
    }
  }

  #pragma unroll
  for (int c = 0; c < 4; ++c) {
    const int gq = ((m0 + c * 16) >> 2) + quad;
    const int pgx = gq % 112, tq = gq / 112;
    const int pgy = tq % 112, nq = tq / 112;
    const bool f0 = (acc[c][0][0] > POT1_T) | (acc[c][0][1] > POT1_T) |
                    (acc[c][0][2] > POT1_T) | (acc[c][0][3] > POT1_T);
    const bool f1 = (acc[c][1][0] > POT1_T) | (acc[c][1][1] > POT1_T) |
                    (acc[c][1][2] > POT1_T) | (acc[c][1][3] > POT1_T);
    const size_t o = ((size_t)(nq * 114 + pgy + 1) * 114 + (pgx + 1)) * 32 + nl;
    spk16[o] = f0 ? (unsigned short)0x3C00 : (unsigned short)0;
    // ch>=30 weights are zero-packed -> acc==0 -> stores 0 (inits ch 30/31)
    spk16[o + 16] = f1 ? (unsigned short)0x3C00 : (unsigned short)0;
  }
}

// ---------------------------------------------------------------------------
// conv2 + fire: block = 4 waves x M=64 = 256 rows; N = 5 subtiles (80 ch),
// 3 N-tiles cover 240. r10: A staged in LDS — block's 256-m run touches
// <=6 consecutive spike-map rows = ONE contiguous 43.8KB region; bulk
// coalesced copy once per block, then all inner A-reads are ds_read_b128
// (kills the HBM-latency chains that r6 exposed: 449MB FETCH, 39% BW,
// pipes idle). B direct from global (135KB, L2-hot, r5-neutral).
// Block-wide transpose epilogue (r8) + nt stores (r9: plain regressed).
// LDS 60KB -> 2 blocks/CU. grid 2208 x 256, chunked-XCD swizzle.
// ---------------------------------------------------------------------------
#define C2_NSUB 5
__global__ __launch_bounds__(256, 2) void conv2_mfma(
    const unsigned short* __restrict__ spk16,
    const unsigned short* __restrict__ bp2,
    float* __restrict__ out_spk, float* __restrict__ out_pot)
{
  __shared__ __attribute__((aligned(16))) unsigned short Alds[6 * 114 * 32]; // 43.8KB
  __shared__ __attribute__((aligned(16))) float Tlds[4096];                  // 16KB

  const int tid = threadIdx.x;

  // chunked-XCD swizzle: gid -> (bx, ntile)
  const int gid = blockIdx.x;                  // 0..2207
  const int xcd = gid & 7, pos = gid >> 3;     // pos 0..275
  const int bxq = pos / 3;                     // 0..91
  const int bx = xcd * 92 + bxq;               // 0..735
  const int ntile = pos - bxq * 3;             // 0..2
  if (bx >= 735) return;                       // 3 idle blocks (uniform exit)

  // block's flat-contiguous output run: 12544 = 49*256 -> never crosses n
  const int nrb = bx / 49;
  const int offb = (bx - nrb * 49) * 256;

  // ---- stage A: rows y_min..y_min+nrows-1, one contiguous region ----
  const int y_min = offb / 112;                // 0..109
  const int nrows = (114 - y_min < 6) ? (114 - y_min) : 6;
  const uint4* asrc =
      (const uint4*)(spk16 + (size_t)(nrb * 114 + y_min) * 114 * 32);
  const int nu4 = nrows * 456;                 // 456 uint4 per row (7296B)
  for (int i = tid; i < nu4; i += 256)
    ((uint4*)Alds)[i] = asrc[i];
  __syncthreads();

  const int wave = tid >> 6, lane = tid & 63;
  const int quad = lane >> 4, nl = lane & 15;
  const int m0 = bx * 256 + wave * 64;         // per-wave 64-m run

  // per-lane LDS A offsets (f16 units), one per chunk
  int aoff[4];
  #pragma unroll
  for (int c = 0; c < 4; ++c) {
    const int m = m0 + c * 16 + nl;
    const int x = m % 112, t = m / 112;
    const int y = t % 112;                     // same n = nrb for all
    aoff[c] = ((y - y_min) * 114 + x) * 32 + quad * 8;
  }

  const half8* bglob = (const half8*)bp2;      // [s*15 + nsub][lane][8]

  #pragma unroll
  for (int g = 0; g < 2; ++g) {
    const int ub = g ? 3 : 0;                  // subtile base of this group
    const int uc = g ? 2 : 3;                  // subtiles in this group

    f32x4 acc[4][3];
    #pragma unroll
    for (int c = 0; c < 4; ++c)
      #pragma unroll
      for (int u2 = 0; u2 < 3; ++u2) acc[c][u2] = (f32x4){0.f, 0.f, 0.f, 0.f};

    #pragma unroll
    for (int s = 0; s < 9; ++s) {              // s = ky*3+kx
      const int ky = s / 3, kx = s - ky * 3;   // compile-time under unroll
      half8 a[4];
      #pragma unroll
      for (int c = 0; c < 4; ++c)
        a[c] = *(const half8*)(Alds + aoff[c] + (ky * 114 + kx) * 32);
      #pragma unroll
      for (int u2 = 0; u2 < 3; ++u2) {
        if (u2 < uc) {
          const half8 b = bglob[(s * 15 + ntile * C2_NSUB + ub + u2) * 64 + lane];
          #pragma unroll
          for (int c = 0; c < 4; ++c)
            acc[c][u2] = __builtin_amdgcn_mfma_f32_16x16x32_f16(a[c], b, acc[c][u2], 0, 0, 0);
        }
      }
    }

    // ---- block-wide transpose epilogue: 1KB single-channel nt stores ----
    // acc[c][u2][rr] @ lane(quad,nl), wave w = pot(m = m0 + (c*4+quad)*4+rr,
    //                                              ch = chbase + nl).
    // Logical T[ch][chunk j][4], j = w*16 + c*4 + quad; phys float off =
    // ch*256 + (j ^ (ch&7))*4 (bank-clean both phases). Store: wave w
    // covers ch w*4..w*4+3; lane l reads chunk j=l -> 1KB contiguous run.
    #pragma unroll
    for (int u2 = 0; u2 < 3; ++u2) {
      if (u2 < uc) {
        __syncthreads();                       // prior store-phase reads done
        #pragma unroll
        for (int c = 0; c < 4; ++c) {
          const int j = wave * 16 + c * 4 + quad;
          *(f32x4*)(Tlds + nl * 256 + ((j ^ (nl & 7)) << 2)) = acc[c][u2];
        }
        __syncthreads();                       // dump visible to all waves
        const int chb = (ntile * C2_NSUB + ub + u2) * 16;
        #pragma unroll
        for (int k = 0; k < 4; ++k) {
          const int chr = wave * 4 + k;        // source channel 0..15
          const f32x4 p4 =
              *(const f32x4*)(Tlds + chr * 256 + ((lane ^ (chr & 7)) << 2));
          const size_t dst =
              (size_t)(nrb * 240 + chb + chr) * 12544 + offb + lane * 4;
          f32x4 sp, pt;
          #pragma unroll
          for (int rr = 0; rr < 4; ++rr) {
            const bool f = p4[rr] > POT2_T;
            sp[rr] = f ? 1.0f : 0.0f;
            pt[rr] = f ? p4[rr] : 0.0f;
          }
          __builtin_nontemporal_store(sp, (f32x4*)(out_spk + dst));
          __builtin_nontemporal_store(pt, (f32x4*)(out_pot + dst));
        }
      }
    }
    __builtin_amdgcn_sched_barrier(0);
  }
}

// ---------------------------------------------------------------------------
extern "C" void kernel_launch(void* const* d_in, const int* in_sizes, int n_in,
                              void* d_out, int out_size, void* d_ws, size_t ws_size,
                              hipStream_t stream)
{
  const float* in = (const float*)d_in[0];
  const float* w1 = (const float*)d_in[1];
  const float* w2 = (const float*)d_in[2];
  float* out = (float*)d_out;

  unsigned short* spk16 = (unsigned short*)d_ws;
  unsigned short* bp2   = (unsigned short*)((char*)d_ws + BP2_OFF);
  unsigned short* bp1   = (unsigned short*)((char*)d_ws + BP1_OFF);
  unsigned short* ina   = (unsigned short*)((char*)d_ws + IN16_OFF);

  prep<<<PAD_BLOCKS + 151 + RING_BLOCKS, 256, 0, stream>>>(
      in, w1, w2, ina, bp2, bp1, spk16);
  conv1_mfma<<<2940, 256, 0, stream>>>(ina, bp1, spk16);
  conv2_mfma<<<2208, 256, 0, stream>>>(
      spk16, bp2, out, out + (size_t)15 * 240 * 112 * 112);
}